// Round 5
// baseline (283.399 us; speedup 1.0000x reference)
//
#include <hip/hip_runtime.h>
#include <stdint.h>

// Three-phase fused causal linear attention (B=4 H=16 T=2048 D=128, fp32 io):
//   out[b,h,i,:] = sum_{j<=i} (q_i . k_j) * v_j
// A1 k_cstate (1024 blocks, (bh,c)): S_c = K_c^T V_c partial (bf16 frag
//    layout -> ws), AND dumps K(row-major) + V^T as bf16, XOR-swizzled, into
//    d_out's own (bh,c) 64KB byte-range (record size == chunk out size, so
//    each k_out block reads only its own record before overwriting it).
// A2 k_prefix (512 blocks): in-place exclusive prefix over the 16 ws records
//    per bh (fp32 accumulate of bf16 partials).  Record 0 becomes zeros.
// B  k_out (1024 blocks, (bh,c)): O_c = Q_c @ S_pre(c) + tril(Q_c K_c^T) V_c.
//    ALL staging via VGPR-free global_load_lds (96KB in flight per CU);
//    only Q goes through registers.  v4's B was in-flight-bytes limited
//    (24 reg loads vs ~40 free VGPRs -> ~5 serialized latency groups).
#define SEQ    2048
#define DIM    128
#define CHUNK  128
#define NCHUNK 16
#define NBH    64
#define RECSH  16384        // shorts per (bh,c) ws state record
#define KVSH   32768        // shorts per (bh,c) K/V record in d_out

typedef __attribute__((ext_vector_type(8))) short short8;   // 8 bf16
typedef __attribute__((ext_vector_type(4))) float floatx4;  // MFMA acc

#define MFMA(a, b, c) __builtin_amdgcn_mfma_f32_16x16x32_bf16((a), (b), (c), 0, 0, 0)

__device__ __forceinline__ short f2bf(float f) {
  union { float f; uint32_t u; } x; x.f = f;
  uint32_t r = x.u + 0x7fffu + ((x.u >> 16) & 1u);   // RNE
  return (short)(r >> 16);
}
__device__ __forceinline__ float bf2f(short s) {
  union { uint32_t u; float f; } x;
  x.u = ((uint32_t)(uint16_t)s) << 16;
  return x.f;
}
__device__ __forceinline__ short8 pack8(const float4 a, const float4 b) {
  short8 s;
  s[0] = f2bf(a.x); s[1] = f2bf(a.y); s[2] = f2bf(a.z); s[3] = f2bf(a.w);
  s[4] = f2bf(b.x); s[5] = f2bf(b.y); s[6] = f2bf(b.z); s[7] = f2bf(b.w);
  return s;
}
// async 16B HBM->LDS; dest must be wave-uniform base + lane*16.
__device__ __forceinline__ void gload16(const void* g, void* l) {
  __builtin_amdgcn_global_load_lds(
      (const __attribute__((address_space(1))) void*)g,
      (__attribute__((address_space(3))) void*)l, 16, 0, 0);
}
// swizzled short-offset inside a [128][128]-short tile (granule-aligned XOR,
// involution; kills the 256B-row same-bank pattern per guide G4).
__device__ __forceinline__ int swz(int row, int colsh) {
  return row * 128 + (colsh ^ ((row & 7) << 3));
}

// ---------------------------------------------------------------------------
// A1: per-chunk state S_c = K_c^T V_c (bf16 frag layout -> ws) + bf16 K/V^T
// dumps (swizzled) into d_out record (bh,c).
__global__ __launch_bounds__(512, 2) void k_cstate(
    const float* __restrict__ kin, const float* __restrict__ vin,
    short* __restrict__ ws, short* outw) {
  const int blk = blockIdx.x;
  const int bh  = blk & 63;              // bh%8 -> XCD, shared with A2/B
  const int c   = blk >> 6;
  const size_t base = (size_t)bh * SEQ * DIM + (size_t)c * CHUNK * DIM;
  const float* kc = kin + base;
  const float* vc = vin + base;
  short* rec = outw + (size_t)(bh * NCHUNK + c) * KVSH;

  __shared__ short Kt[128][136];   // K^T bf16: Kt[d'][j]; later reused as Ss
  __shared__ short Vt[128][136];   // V^T bf16: Vt[d][j]

  const int tid  = threadIdx.x;
  const int wave = tid >> 6;
  const int lane = tid & 63;
  const int q4   = lane >> 4;
  const int l16  = lane & 15;
  const int j    = tid & 127;
  const int dhi  = tid >> 7;

  // ---- stage K^T / V^T into LDS + dump K row-major bf16 (swizzled) ----
#pragma unroll
  for (int it = 0; it < 4; ++it) {
    const int d0 = it * 32 + dhi * 8;
    const float* krow = kc + (size_t)j * DIM + d0;
    const float4 ka = *(const float4*)krow;
    const float4 kb2 = *(const float4*)(krow + 4);
    Kt[d0 + 0][j] = f2bf(ka.x); Kt[d0 + 1][j] = f2bf(ka.y);
    Kt[d0 + 2][j] = f2bf(ka.z); Kt[d0 + 3][j] = f2bf(ka.w);
    Kt[d0 + 4][j] = f2bf(kb2.x); Kt[d0 + 5][j] = f2bf(kb2.y);
    Kt[d0 + 6][j] = f2bf(kb2.z); Kt[d0 + 7][j] = f2bf(kb2.w);
    *(short8*)&rec[swz(j, d0)] = pack8(ka, kb2);       // K row-major dump
    const float* vrow = vc + (size_t)j * DIM + d0;
    const float4 va = *(const float4*)vrow;
    const float4 vb2 = *(const float4*)(vrow + 4);
    Vt[d0 + 0][j] = f2bf(va.x); Vt[d0 + 1][j] = f2bf(va.y);
    Vt[d0 + 2][j] = f2bf(va.z); Vt[d0 + 3][j] = f2bf(va.w);
    Vt[d0 + 4][j] = f2bf(vb2.x); Vt[d0 + 5][j] = f2bf(vb2.y);
    Vt[d0 + 6][j] = f2bf(vb2.z); Vt[d0 + 7][j] = f2bf(vb2.w);
  }
  __syncthreads();

  // ---- dump V^T bf16 (swizzled) from LDS: full 256B rows per 16 lanes ----
#pragma unroll
  for (int i = 0; i < 4; ++i) {
    const int g = i * 512 + tid;
    const int r = g >> 4, cg = g & 15;
    *(short8*)&rec[16384 + swz(r, cg * 8)] = *(const short8*)&Vt[r][cg * 8];
  }

  // ---- S^T[d][d'] = sum_j V^T[d][j] K[j][d'] ----
  floatx4 acc[8];
#pragma unroll
  for (int m = 0; m < 8; ++m)
#pragma unroll
    for (int r = 0; r < 4; ++r) acc[m][r] = 0.f;
#pragma unroll
  for (int ks = 0; ks < 4; ++ks) {
    const short8 bk = *(const short8*)&Kt[wave * 16 + l16][ks * 32 + q4 * 8];
#pragma unroll
    for (int m = 0; m < 8; ++m) {
      const short8 av = *(const short8*)&Vt[m * 16 + l16][ks * 32 + q4 * 8];
      acc[m] = MFMA(av, bk, acc[m]);
    }
  }
  __syncthreads();                 // all Kt reads done; reuse as Ss

  // ---- dump acc -> Ss[d][d'] (bf16) ----
  short (*Ss)[136] = (short (*)[136])Kt;
#pragma unroll
  for (int m = 0; m < 8; ++m)
#pragma unroll
    for (int r = 0; r < 4; ++r)
      Ss[m * 16 + q4 * 4 + r][wave * 16 + l16] = f2bf(acc[m][r]);
  __syncthreads();

  // ---- copy Ss -> ws record in frag layout (verified mapping) ----
  short* srec = ws + (size_t)(bh * NCHUNK + c) * RECSH;
#pragma unroll
  for (int i = 0; i < 4; ++i) {
    const int t8  = i * 512 + tid;
    const int row = ((t8 >> 9) << 5) + (((t8 >> 6) & 1) << 4) + (t8 & 15);
    const int col = (((t8 >> 7) & 3) << 5) + (((t8 >> 4) & 3) << 3);
    *(short8*)&srec[(size_t)t8 * 8] = *(const short8*)&Ss[row][col];
  }
}

// ---------------------------------------------------------------------------
// A2: in-place exclusive prefix over the 16 ws records of each bh.
__global__ __launch_bounds__(256, 4) void k_prefix(short* __restrict__ ws) {
  const int blk = blockIdx.x;
  const int bh  = blk & 63;              // bh%8 -> XCD, shared with A1/B
  const int p   = blk >> 6;
  const int off = p * 2048 + threadIdx.x * 8;
  short* wb = ws + (size_t)bh * NCHUNK * RECSH;

  float run[8];
#pragma unroll
  for (int s = 0; s < 8; ++s) run[s] = 0.f;
#pragma unroll
  for (int cc = 0; cc < NCHUNK; ++cc) {
    short8* ptr = (short8*)&wb[(size_t)cc * RECSH + off];
    const short8 rv = *ptr;              // read partial S_cc
    short8 ov;
#pragma unroll
    for (int s = 0; s < 8; ++s) ov[s] = f2bf(run[s]);
    *ptr = ov;                           // write exclusive prefix (c=0 -> 0)
#pragma unroll
    for (int s = 0; s < 8; ++s) run[s] += bf2f(rv[s]);
  }
}

// ---------------------------------------------------------------------------
// B: one block per (bh, chunk).  Staging: 12 VGPR-free gload16 (K, V^T, Sb)
// + 8 Q register loads.  KVS layout: [0,16K) K-swz, [16K,32K) Vt-swz,
// [32K,48K) Sb frag blob.  K region is overwritten by masked P after the
// score phase (same-wave PV reads only).
__global__ __launch_bounds__(512, 2) void k_out(
    const float* __restrict__ qin, const short* __restrict__ ws,
    float* out) {
  const int blk = blockIdx.x;
  const int bh  = blk & 63;              // bh%8 -> XCD, shared with A1/A2
  const int c   = blk >> 6;
  const size_t base = (size_t)bh * SEQ * DIM + (size_t)c * CHUNK * DIM;
  const float* qc = qin + base;
  float* oc = out + base;
  const short* rec = (const short*)out + (size_t)(bh * NCHUNK + c) * KVSH;

  __shared__ __align__(16) short KVS[49152];

  const int tid  = threadIdx.x;
  const int wave = tid >> 6;
  const int lane = tid & 63;
  const int q4   = lane >> 4;
  const int l16  = lane & 15;

  // ---- issue ALL async staging first (VGPR-free, deep queue) ----
#pragma unroll
  for (int i = 0; i < 8; ++i) {          // K + V^T records (pre-swizzled)
    const int g = i * 512 + tid;
    gload16(&rec[(size_t)g * 8], &KVS[(size_t)g * 8]);
  }
  const short* sp = ws + (size_t)(bh * NCHUNK + c) * RECSH;
#pragma unroll
  for (int i = 0; i < 4; ++i) {          // S_pre frag blob
    const int g = i * 512 + tid;
    gload16(&sp[(size_t)g * 8], &KVS[32768 + (size_t)g * 8]);
  }

  // ---- Q fragments through registers ----
  const float* qrow = qc + (size_t)(wave * 16 + l16) * DIM + q4 * 8;
  short8 aq[4];
#pragma unroll
  for (int ks = 0; ks < 4; ++ks)
    aq[ks] = pack8(*(const float4*)(qrow + ks * 32),
                   *(const float4*)(qrow + ks * 32 + 4));
  __syncthreads();   // drains vmcnt: KVS fully landed

  floatx4 oacc[8];
#pragma unroll
  for (int tn = 0; tn < 8; ++tn)
#pragma unroll
    for (int r = 0; r < 4; ++r) oacc[tn][r] = 0.f;

  // ---- inter-chunk part: O += Q @ S_pre (B-frags from Sb region) ----
#pragma unroll
  for (int ks = 0; ks < 4; ++ks)
#pragma unroll
    for (int tn = 0; tn < 8; ++tn) {
      const short8 bs = *(const short8*)
          &KVS[32768 + (tn >> 1) * 4096 + ks * 1024 + (tn & 1) * 512 + lane * 8];
      oacc[tn] = MFMA(aq[ks], bs, oacc[tn]);
    }

  // ---- intra-chunk causal scores for i-tile `wave`, held in registers ----
  floatx4 sacc[8];
#pragma unroll
  for (int tj = 0; tj < 8; ++tj) {
    if (tj > wave) continue;             // wave-uniform, tj static
#pragma unroll
    for (int r = 0; r < 4; ++r) sacc[tj][r] = 0.f;
#pragma unroll
    for (int ks = 0; ks < 4; ++ks) {
      const short8 bk =
          *(const short8*)&KVS[swz(tj * 16 + l16, ks * 32 + q4 * 8)];
      sacc[tj] = MFMA(aq[ks], bk, sacc[tj]);
    }
  }
  __syncthreads();   // all K reads done; K region becomes the P buffer

  // ---- masked P into K region (each wave writes only its own 16 rows) ----
#pragma unroll
  for (int tj = 0; tj < 8; ++tj) {
    if (tj > wave) continue;
#pragma unroll
    for (int r = 0; r < 4; ++r) {
      float val = sacc[tj][r];
      if (tj == wave && l16 > q4 * 4 + r) val = 0.f;   // strict-upper mask
      KVS[swz(wave * 16 + q4 * 4 + r, tj * 16 + l16)] = f2bf(val);
    }
  }
  if ((wave & 1) == 0) {   // even wave: zero tile wave+1 (PV k-step pad)
#pragma unroll
    for (int r = 0; r < 4; ++r)
      KVS[swz(wave * 16 + q4 * 4 + r, (wave + 1) * 16 + l16)] = 0;
  }

  // ---- PV: same-wave P rows (no barrier needed) ----
  const int kst = (wave + 2) >> 1;
  for (int t = 0; t < kst; ++t) {
    const short8 ap =
        *(const short8*)&KVS[swz(wave * 16 + l16, t * 32 + q4 * 8)];
#pragma unroll
    for (int tn = 0; tn < 8; ++tn) {
      const short8 bv =
          *(const short8*)&KVS[16384 + swz(tn * 16 + l16, t * 32 + q4 * 8)];
      oacc[tn] = MFMA(ap, bv, oacc[tn]);
    }
  }

  // ---- write out tile (fp32), overwriting this block's own record ----
#pragma unroll
  for (int tn = 0; tn < 8; ++tn)
#pragma unroll
    for (int r = 0; r < 4; ++r)
      oc[(size_t)(wave * 16 + q4 * 4 + r) * DIM + tn * 16 + l16] = oacc[tn][r];
}

// ---------------------------------------------------------------------------
extern "C" void kernel_launch(void* const* d_in, const int* in_sizes, int n_in,
                              void* d_out, int out_size, void* d_ws, size_t ws_size,
                              hipStream_t stream) {
  const float* q = (const float*)d_in[0];
  const float* k = (const float*)d_in[1];
  const float* v = (const float*)d_in[2];
  float* out = (float*)d_out;
  (void)in_sizes; (void)n_in; (void)out_size; (void)ws_size;
  // requires ws_size >= 64*16*16384*2 = 32 MiB
  short* ws = (short*)d_ws;

  hipLaunchKernelGGL(k_cstate, dim3(NBH * NCHUNK), dim3(512), 0, stream,
                     k, v, ws, (short*)d_out);
  hipLaunchKernelGGL(k_prefix, dim3(NBH * 8), dim3(256), 0, stream, ws);
  hipLaunchKernelGGL(k_out, dim3(NBH * NCHUNK), dim3(512), 0, stream,
                     q, ws, out);
}

// Round 6
// 273.721 us; speedup vs baseline: 1.0354x; 1.0354x over previous
//
#include <hip/hip_runtime.h>
#include <stdint.h>

// Three-phase fused causal linear attention (B=4 H=16 T=2048 D=128, fp32 io):
//   out[b,h,i,:] = sum_{j<=i} (q_i . k_j) * v_j
// A1 k_cstate (1024 blocks, (bh,c)): S_c = K_c^T V_c partial (bf16 frag
//    layout -> ws), AND dumps K(row-major) + V^T as bf16, XOR-swizzled, into
//    d_out's own (bh,c) 64KB byte-range.  v6: record dumps are COALESCED
//    (v5 scattered 16B stores caused partial-line RMW: WRITE 122MB vs 96MB
//    written).  Record layout is bit-identical to v5's (granule pg of row r
//    holds cols (pg^(r&7))*8..+8); the K dump reads global fp32 at the
//    permuted column instead, and stores the record linearly.  Staging is
//    load-all-then-convert with sched_barrier(0) so the 16 float4 loads
//    stay in flight (v1 lesson: compiler sinks loads into converts).
// A2 k_prefix (512 blocks): in-place exclusive prefix over the 16 ws records
//    per bh (fp32 accumulate of bf16 partials).  Record 0 becomes zeros.
// B  k_out (1024 blocks, (bh,c)): O_c = Q_c @ S_pre(c) + tril(Q_c K_c^T) V_c.
//    ALL staging via VGPR-free global_load_lds; only Q through registers.
//    (v5 confirmed: 72 -> ~44us when B went all-gload.)
#define SEQ    2048
#define DIM    128
#define CHUNK  128
#define NCHUNK 16
#define NBH    64
#define RECSH  16384        // shorts per (bh,c) ws state record
#define KVSH   32768        // shorts per (bh,c) K/V record in d_out

typedef __attribute__((ext_vector_type(8))) short short8;   // 8 bf16
typedef __attribute__((ext_vector_type(4))) float floatx4;  // MFMA acc

#define MFMA(a, b, c) __builtin_amdgcn_mfma_f32_16x16x32_bf16((a), (b), (c), 0, 0, 0)

__device__ __forceinline__ short f2bf(float f) {
  union { float f; uint32_t u; } x; x.f = f;
  uint32_t r = x.u + 0x7fffu + ((x.u >> 16) & 1u);   // RNE
  return (short)(r >> 16);
}
__device__ __forceinline__ float bf2f(short s) {
  union { uint32_t u; float f; } x;
  x.u = ((uint32_t)(uint16_t)s) << 16;
  return x.f;
}
__device__ __forceinline__ short8 pack8(const float4 a, const float4 b) {
  short8 s;
  s[0] = f2bf(a.x); s[1] = f2bf(a.y); s[2] = f2bf(a.z); s[3] = f2bf(a.w);
  s[4] = f2bf(b.x); s[5] = f2bf(b.y); s[6] = f2bf(b.z); s[7] = f2bf(b.w);
  return s;
}
// async 16B HBM->LDS; dest must be wave-uniform base + lane*16.
__device__ __forceinline__ void gload16(const void* g, void* l) {
  __builtin_amdgcn_global_load_lds(
      (const __attribute__((address_space(1))) void*)g,
      (__attribute__((address_space(3))) void*)l, 16, 0, 0);
}
// swizzled short-offset inside a [128][128]-short tile (granule-aligned XOR,
// involution; kills the 256B-row same-bank pattern per guide G4).
__device__ __forceinline__ int swz(int row, int colsh) {
  return row * 128 + (colsh ^ ((row & 7) << 3));
}

// ---------------------------------------------------------------------------
// A1: per-chunk state S_c = K_c^T V_c (bf16 frag layout -> ws) + bf16 K/V^T
// record dumps (swizzled layout, coalesced writes) into d_out record (bh,c).
__global__ __launch_bounds__(512, 2) void k_cstate(
    const float* __restrict__ kin, const float* __restrict__ vin,
    short* __restrict__ ws, short* outw) {
  const int blk = blockIdx.x;
  const int bh  = blk & 63;              // bh%8 -> XCD, shared with A2/B
  const int c   = blk >> 6;
  const size_t base = (size_t)bh * SEQ * DIM + (size_t)c * CHUNK * DIM;
  const float* kc = kin + base;
  const float* vc = vin + base;
  short* rec = outw + (size_t)(bh * NCHUNK + c) * KVSH;

  __shared__ short Kt[128][136];   // K^T bf16: Kt[d'][j]; later reused as Ss
  __shared__ short Vt[128][136];   // V^T bf16: Vt[d][j]

  const int tid  = threadIdx.x;
  const int wave = tid >> 6;
  const int lane = tid & 63;
  const int q4   = lane >> 4;
  const int l16  = lane & 15;

  // ---- phase L: pure loads, kept in flight (fence below) ----
  // thread owns record granules g = i*512+tid; K read at the PERMUTED
  // column so the linear record store yields the v5 (verified) layout.
  float4 kA[4][2], vA[4][2];
#pragma unroll
  for (int i = 0; i < 4; ++i) {
    const int g = i * 512 + tid;
    const int r = g >> 4, pg = g & 15;
    const float* kp = kc + (size_t)r * DIM + ((pg ^ (r & 7)) << 3);
    kA[i][0] = *(const float4*)kp;
    kA[i][1] = *(const float4*)(kp + 4);
    const float* vp = vc + (size_t)r * DIM + (pg << 3);
    vA[i][0] = *(const float4*)vp;
    vA[i][1] = *(const float4*)(vp + 4);
  }
  __builtin_amdgcn_sched_barrier(0);   // loads issued before any convert

  // ---- phase C: convert + K record (linear, coalesced) + Kt/Vt stage ----
#pragma unroll
  for (int i = 0; i < 4; ++i) {
    const int g = i * 512 + tid;
    const int r = g >> 4, pg = g & 15;
    *(short8*)&rec[(size_t)g * 8] = pack8(kA[i][0], kA[i][1]);
    const int ck = (pg ^ (r & 7)) << 3;      // K col base (permuted read)
    Kt[ck + 0][r] = f2bf(kA[i][0].x); Kt[ck + 1][r] = f2bf(kA[i][0].y);
    Kt[ck + 2][r] = f2bf(kA[i][0].z); Kt[ck + 3][r] = f2bf(kA[i][0].w);
    Kt[ck + 4][r] = f2bf(kA[i][1].x); Kt[ck + 5][r] = f2bf(kA[i][1].y);
    Kt[ck + 6][r] = f2bf(kA[i][1].z); Kt[ck + 7][r] = f2bf(kA[i][1].w);
    const int cv = pg << 3;                  // V col base (natural read)
    Vt[cv + 0][r] = f2bf(vA[i][0].x); Vt[cv + 1][r] = f2bf(vA[i][0].y);
    Vt[cv + 2][r] = f2bf(vA[i][0].z); Vt[cv + 3][r] = f2bf(vA[i][0].w);
    Vt[cv + 4][r] = f2bf(vA[i][1].x); Vt[cv + 5][r] = f2bf(vA[i][1].y);
    Vt[cv + 6][r] = f2bf(vA[i][1].z); Vt[cv + 7][r] = f2bf(vA[i][1].w);
  }
  __syncthreads();

  // ---- V^T record dump: vector LDS read at XOR'd granule, linear store ----
#pragma unroll
  for (int i = 0; i < 4; ++i) {
    const int g = i * 512 + tid;
    const int r = g >> 4, pg = g & 15;
    *(short8*)&rec[16384 + (size_t)g * 8] =
        *(const short8*)&Vt[r][(pg ^ (r & 7)) << 3];
  }

  // ---- S^T[d][d'] = sum_j V^T[d][j] K[j][d'] ----
  floatx4 acc[8];
#pragma unroll
  for (int m = 0; m < 8; ++m)
#pragma unroll
    for (int r = 0; r < 4; ++r) acc[m][r] = 0.f;
#pragma unroll
  for (int ks = 0; ks < 4; ++ks) {
    const short8 bk = *(const short8*)&Kt[wave * 16 + l16][ks * 32 + q4 * 8];
#pragma unroll
    for (int m = 0; m < 8; ++m) {
      const short8 av = *(const short8*)&Vt[m * 16 + l16][ks * 32 + q4 * 8];
      acc[m] = MFMA(av, bk, acc[m]);
    }
  }
  __syncthreads();                 // all Kt reads done; reuse as Ss

  // ---- dump acc -> Ss[d][d'] (bf16) ----
  short (*Ss)[136] = (short (*)[136])Kt;
#pragma unroll
  for (int m = 0; m < 8; ++m)
#pragma unroll
    for (int r = 0; r < 4; ++r)
      Ss[m * 16 + q4 * 4 + r][wave * 16 + l16] = f2bf(acc[m][r]);
  __syncthreads();

  // ---- copy Ss -> ws record in frag layout (verified mapping) ----
  short* srec = ws + (size_t)(bh * NCHUNK + c) * RECSH;
#pragma unroll
  for (int i = 0; i < 4; ++i) {
    const int t8  = i * 512 + tid;
    const int row = ((t8 >> 9) << 5) + (((t8 >> 6) & 1) << 4) + (t8 & 15);
    const int col = (((t8 >> 7) & 3) << 5) + (((t8 >> 4) & 3) << 3);
    *(short8*)&srec[(size_t)t8 * 8] = *(const short8*)&Ss[row][col];
  }
}

// ---------------------------------------------------------------------------
// A2: in-place exclusive prefix over the 16 ws records of each bh.
__global__ __launch_bounds__(256, 4) void k_prefix(short* __restrict__ ws) {
  const int blk = blockIdx.x;
  const int bh  = blk & 63;              // bh%8 -> XCD, shared with A1/B
  const int p   = blk >> 6;
  const int off = p * 2048 + threadIdx.x * 8;
  short* wb = ws + (size_t)bh * NCHUNK * RECSH;

  float run[8];
#pragma unroll
  for (int s = 0; s < 8; ++s) run[s] = 0.f;
#pragma unroll
  for (int cc = 0; cc < NCHUNK; ++cc) {
    short8* ptr = (short8*)&wb[(size_t)cc * RECSH + off];
    const short8 rv = *ptr;              // read partial S_cc
    short8 ov;
#pragma unroll
    for (int s = 0; s < 8; ++s) ov[s] = f2bf(run[s]);
    *ptr = ov;                           // write exclusive prefix (c=0 -> 0)
#pragma unroll
    for (int s = 0; s < 8; ++s) run[s] += bf2f(rv[s]);
  }
}

// ---------------------------------------------------------------------------
// B: one block per (bh, chunk).  Staging: 12 VGPR-free gload16 (K, V^T, Sb)
// + 8 Q register loads.  KVS layout: [0,16K) K-swz, [16K,32K) Vt-swz,
// [32K,48K) Sb frag blob.  K region is overwritten by masked P after the
// score phase (same-wave PV reads only).
__global__ __launch_bounds__(512, 2) void k_out(
    const float* __restrict__ qin, const short* __restrict__ ws,
    float* out) {
  const int blk = blockIdx.x;
  const int bh  = blk & 63;              // bh%8 -> XCD, shared with A1/A2
  const int c   = blk >> 6;
  const size_t base = (size_t)bh * SEQ * DIM + (size_t)c * CHUNK * DIM;
  const float* qc = qin + base;
  float* oc = out + base;
  const short* rec = (const short*)out + (size_t)(bh * NCHUNK + c) * KVSH;

  __shared__ __align__(16) short KVS[49152];

  const int tid  = threadIdx.x;
  const int wave = tid >> 6;
  const int lane = tid & 63;
  const int q4   = lane >> 4;
  const int l16  = lane & 15;

  // ---- issue ALL async staging first (VGPR-free, deep queue) ----
#pragma unroll
  for (int i = 0; i < 8; ++i) {          // K + V^T records (pre-swizzled)
    const int g = i * 512 + tid;
    gload16(&rec[(size_t)g * 8], &KVS[(size_t)g * 8]);
  }
  const short* sp = ws + (size_t)(bh * NCHUNK + c) * RECSH;
#pragma unroll
  for (int i = 0; i < 4; ++i) {          // S_pre frag blob
    const int g = i * 512 + tid;
    gload16(&sp[(size_t)g * 8], &KVS[32768 + (size_t)g * 8]);
  }

  // ---- Q fragments through registers ----
  const float* qrow = qc + (size_t)(wave * 16 + l16) * DIM + q4 * 8;
  short8 aq[4];
#pragma unroll
  for (int ks = 0; ks < 4; ++ks)
    aq[ks] = pack8(*(const float4*)(qrow + ks * 32),
                   *(const float4*)(qrow + ks * 32 + 4));
  __syncthreads();   // drains vmcnt: KVS fully landed

  floatx4 oacc[8];
#pragma unroll
  for (int tn = 0; tn < 8; ++tn)
#pragma unroll
    for (int r = 0; r < 4; ++r) oacc[tn][r] = 0.f;

  // ---- inter-chunk part: O += Q @ S_pre (B-frags from Sb region) ----
#pragma unroll
  for (int ks = 0; ks < 4; ++ks)
#pragma unroll
    for (int tn = 0; tn < 8; ++tn) {
      const short8 bs = *(const short8*)
          &KVS[32768 + (tn >> 1) * 4096 + ks * 1024 + (tn & 1) * 512 + lane * 8];
      oacc[tn] = MFMA(aq[ks], bs, oacc[tn]);
    }

  // ---- intra-chunk causal scores for i-tile `wave`, held in registers ----
  floatx4 sacc[8];
#pragma unroll
  for (int tj = 0; tj < 8; ++tj) {
    if (tj > wave) continue;             // wave-uniform, tj static
#pragma unroll
    for (int r = 0; r < 4; ++r) sacc[tj][r] = 0.f;
#pragma unroll
    for (int ks = 0; ks < 4; ++ks) {
      const short8 bk =
          *(const short8*)&KVS[swz(tj * 16 + l16, ks * 32 + q4 * 8)];
      sacc[tj] = MFMA(aq[ks], bk, sacc[tj]);
    }
  }
  __syncthreads();   // all K reads done; K region becomes the P buffer

  // ---- masked P into K region (each wave writes only its own 16 rows) ----
#pragma unroll
  for (int tj = 0; tj < 8; ++tj) {
    if (tj > wave) continue;
#pragma unroll
    for (int r = 0; r < 4; ++r) {
      float val = sacc[tj][r];
      if (tj == wave && l16 > q4 * 4 + r) val = 0.f;   // strict-upper mask
      KVS[swz(wave * 16 + q4 * 4 + r, tj * 16 + l16)] = f2bf(val);
    }
  }
  if ((wave & 1) == 0) {   // even wave: zero tile wave+1 (PV k-step pad)
#pragma unroll
    for (int r = 0; r < 4; ++r)
      KVS[swz(wave * 16 + q4 * 4 + r, (wave + 1) * 16 + l16)] = 0;
  }

  // ---- PV: same-wave P rows (no barrier needed) ----
  const int kst = (wave + 2) >> 1;
  for (int t = 0; t < kst; ++t) {
    const short8 ap =
        *(const short8*)&KVS[swz(wave * 16 + l16, t * 32 + q4 * 8)];
#pragma unroll
    for (int tn = 0; tn < 8; ++tn) {
      const short8 bv =
          *(const short8*)&KVS[16384 + swz(tn * 16 + l16, t * 32 + q4 * 8)];
      oacc[tn] = MFMA(ap, bv, oacc[tn]);
    }
  }

  // ---- write out tile (fp32), overwriting this block's own record ----
#pragma unroll
  for (int tn = 0; tn < 8; ++tn)
#pragma unroll
    for (int r = 0; r < 4; ++r)
      oc[(size_t)(wave * 16 + q4 * 4 + r) * DIM + tn * 16 + l16] = oacc[tn][r];
}

// ---------------------------------------------------------------------------
extern "C" void kernel_launch(void* const* d_in, const int* in_sizes, int n_in,
                              void* d_out, int out_size, void* d_ws, size_t ws_size,
                              hipStream_t stream) {
  const float* q = (const float*)d_in[0];
  const float* k = (const float*)d_in[1];
  const float* v = (const float*)d_in[2];
  float* out = (float*)d_out;
  (void)in_sizes; (void)n_in; (void)out_size; (void)ws_size;
  // requires ws_size >= 64*16*16384*2 = 32 MiB
  short* ws = (short*)d_ws;

  hipLaunchKernelGGL(k_cstate, dim3(NBH * NCHUNK), dim3(512), 0, stream,
                     k, v, ws, (short*)d_out);
  hipLaunchKernelGGL(k_prefix, dim3(NBH * 8), dim3(256), 0, stream, ws);
  hipLaunchKernelGGL(k_out, dim3(NBH * NCHUNK), dim3(512), 0, stream,
                     q, ws, out);
}

// Round 7
// 271.356 us; speedup vs baseline: 1.0444x; 1.0087x over previous
//
#include <hip/hip_runtime.h>
#include <stdint.h>

// Three-phase fused causal linear attention (B=4 H=16 T=2048 D=128, fp32 io):
//   out[b,h,i,:] = sum_{j<=i} (q_i . k_j) * v_j
// A1 k_cstate (1024 blocks, (bh,c)): S_c = K_c^T V_c partial (bf16 frag
//    layout -> ws) + K/V records into d_out's own (bh,c) 64KB range.
//    v7: records are MFMA B-FRAGMENT BLOBS (read linearly by B at lane*8,
//    zero conflicts, no swizzle) -- K-blob is produced register-only
//    (coalesced read, linear store); V-blob from Vt LDS row-granules.
//    Kt/Vt use per-buffer XOR'd internal layouts so the transposed staging
//    writes are bank-spread (v6's 17.2M conflicts were 16-way writes:
//    granule-lanes wrote cols spaced 8*272B = 0 mod 128B).
// A2 k_prefix (512 blocks): in-place exclusive prefix over the 16 ws records
//    per bh (fp32 accumulate of bf16 partials).  Record 0 becomes zeros.
// B  k_out (1024 blocks, (bh,c)): O_c = Q_c @ S_pre(c) + tril(Q_c K_c^T) V_c.
//    ALL staging via VGPR-free global_load_lds; only Q through registers.
//    Score/PV B-frags read LINEARLY from the blobs; P scratch reuses the
//    freed K-blob region with the old swizzled [128][128] layout.
#define SEQ    2048
#define DIM    128
#define CHUNK  128
#define NCHUNK 16
#define NBH    64
#define RECSH  16384        // shorts per (bh,c) ws state record
#define KVSH   32768        // shorts per (bh,c) K/V record in d_out

typedef __attribute__((ext_vector_type(8))) short short8;   // 8 bf16
typedef __attribute__((ext_vector_type(4))) float floatx4;  // MFMA acc

#define MFMA(a, b, c) __builtin_amdgcn_mfma_f32_16x16x32_bf16((a), (b), (c), 0, 0, 0)

__device__ __forceinline__ short f2bf(float f) {
  union { float f; uint32_t u; } x; x.f = f;
  uint32_t r = x.u + 0x7fffu + ((x.u >> 16) & 1u);   // RNE
  return (short)(r >> 16);
}
__device__ __forceinline__ float bf2f(short s) {
  union { uint32_t u; float f; } x;
  x.u = ((uint32_t)(uint16_t)s) << 16;
  return x.f;
}
__device__ __forceinline__ short8 pack8(const float4 a, const float4 b) {
  short8 s;
  s[0] = f2bf(a.x); s[1] = f2bf(a.y); s[2] = f2bf(a.z); s[3] = f2bf(a.w);
  s[4] = f2bf(b.x); s[5] = f2bf(b.y); s[6] = f2bf(b.z); s[7] = f2bf(b.w);
  return s;
}
// async 16B HBM->LDS; dest must be wave-uniform base + lane*16.
__device__ __forceinline__ void gload16(const void* g, void* l) {
  __builtin_amdgcn_global_load_lds(
      (const __attribute__((address_space(1))) void*)g,
      (__attribute__((address_space(3))) void*)l, 16, 0, 0);
}
// B's P-scratch swizzle (block-local [128][128] region, unchanged from v6).
__device__ __forceinline__ int swz(int row, int colsh) {
  return row * 128 + (colsh ^ ((row & 7) << 3));
}
// A1 internal LDS layouts (granule-aligned XOR keyed on the ROW index so
// transposed writes spread banks; reads apply the same key).
__device__ __forceinline__ int kcol(int row, int col) {   // Kt: 32B-granule key
  return col ^ (((row >> 3) & 3) << 4);
}
__device__ __forceinline__ int vcol(int row, int col) {   // Vt: 16B-granule key
  return col ^ (((row >> 3) & 7) << 3);
}

// ---------------------------------------------------------------------------
// A1: per-chunk state S_c = K_c^T V_c (bf16 frag layout -> ws) + K/V frag
// blobs (linear stores) into d_out record (bh,c).
__global__ __launch_bounds__(512, 2) void k_cstate(
    const float* __restrict__ kin, const float* __restrict__ vin,
    short* __restrict__ ws, short* outw) {
  const int blk = blockIdx.x;
  const int bh  = blk & 63;              // bh%8 -> XCD, shared with A2/B
  const int c   = blk >> 6;
  const size_t base = (size_t)bh * SEQ * DIM + (size_t)c * CHUNK * DIM;
  const float* kc = kin + base;
  const float* vc = vin + base;
  short* rec = outw + (size_t)(bh * NCHUNK + c) * KVSH;

  __shared__ short Kt[128][136];   // K^T bf16, kcol layout; later reused as Ss
  __shared__ short Vt[128][136];   // V^T bf16, vcol layout

  const int tid  = threadIdx.x;
  const int wave = tid >> 6;
  const int lane = tid & 63;
  const int q4   = lane >> 4;
  const int l16  = lane & 15;

  // ---- phase L: all 16 float4-pair loads issued, kept in flight ----
  // K: lane owns blob granule g2 = (tj*4+ks)*64 + lane2; reads
  //    K[tj*16+l16g][ks*32+q4g*8 .. +8] (4 q4-lanes cover 128B/row).
  float4 kA[4][2], vA[4][2];
#pragma unroll
  for (int i = 0; i < 4; ++i) {
    const int g2 = i * 512 + tid;
    const int tj = g2 >> 8, ks = (g2 >> 6) & 3, ln = g2 & 63;
    const float* kp =
        kc + (size_t)(tj * 16 + (ln & 15)) * DIM + ks * 32 + (ln >> 4) * 8;
    kA[i][0] = *(const float4*)kp;
    kA[i][1] = *(const float4*)(kp + 4);
    // V: lane owns row-granule (r, pg) for the Vt transpose staging.
    const int g = i * 512 + tid;
    const float* vp = vc + (size_t)(g >> 4) * DIM + (g & 15) * 8;
    vA[i][0] = *(const float4*)vp;
    vA[i][1] = *(const float4*)(vp + 4);
  }
  __builtin_amdgcn_sched_barrier(0);   // loads stay ahead of converts

  // ---- phase C: K blob (linear store) + Kt writes; Vt writes ----
#pragma unroll
  for (int i = 0; i < 4; ++i) {
    const int g2 = i * 512 + tid;
    const int tj = g2 >> 8, ks = (g2 >> 6) & 3, ln = g2 & 63;
    *(short8*)&rec[(size_t)g2 * 8] = pack8(kA[i][0], kA[i][1]);
    const int colb = tj * 16 + (ln & 15);
    const float* kv = (const float*)&kA[i][0];
#pragma unroll
    for (int s = 0; s < 8; ++s) {
      const int r2 = ks * 32 + (ln >> 4) * 8 + s;
      Kt[r2][kcol(r2, colb)] = f2bf(kv[s]);
    }
    const int g = i * 512 + tid;
    const int r = g >> 4, pg = g & 15;
    const float* vv = (const float*)&vA[i][0];
#pragma unroll
    for (int s = 0; s < 8; ++s) {
      const int row = pg * 8 + s;
      Vt[row][vcol(row, r)] = f2bf(vv[s]);
    }
  }
  __syncthreads();

  // ---- V blob: Vt row-granule reads (conflict-free), linear stores ----
#pragma unroll
  for (int i = 0; i < 4; ++i) {
    const int g3 = i * 512 + tid;
    const int tdx = g3 >> 6, ln = g3 & 63;
    const int row = (tdx & 7) * 16 + (ln & 15);          // tn*16 + l16
    const int col = (tdx >> 3) * 32 + (ln >> 4) * 8;     // t*32 + q4*8
    *(short8*)&rec[16384 + (size_t)g3 * 8] =
        *(const short8*)&Vt[row][vcol(row, col)];
  }

  // ---- S^T[d][d'] = sum_j V^T[d][j] K[j][d'] ----
  floatx4 acc[8];
#pragma unroll
  for (int m = 0; m < 8; ++m)
#pragma unroll
    for (int r = 0; r < 4; ++r) acc[m][r] = 0.f;
  const int dp = wave * 16 + l16;
#pragma unroll
  for (int ks = 0; ks < 4; ++ks) {
    const short8 bk = *(const short8*)&Kt[dp][kcol(dp, ks * 32 + q4 * 8)];
#pragma unroll
    for (int m = 0; m < 8; ++m) {
      const int vd = m * 16 + l16;
      const short8 av = *(const short8*)&Vt[vd][vcol(vd, ks * 32 + q4 * 8)];
      acc[m] = MFMA(av, bk, acc[m]);
    }
  }
  __syncthreads();                 // all Kt reads done; reuse as Ss

  // ---- dump acc -> Ss[d][d'] (bf16, plain layout) ----
  short (*Ss)[136] = (short (*)[136])Kt;
#pragma unroll
  for (int m = 0; m < 8; ++m)
#pragma unroll
    for (int r = 0; r < 4; ++r)
      Ss[m * 16 + q4 * 4 + r][wave * 16 + l16] = f2bf(acc[m][r]);
  __syncthreads();

  // ---- copy Ss -> ws record in frag layout (verified mapping) ----
  short* srec = ws + (size_t)(bh * NCHUNK + c) * RECSH;
#pragma unroll
  for (int i = 0; i < 4; ++i) {
    const int t8  = i * 512 + tid;
    const int row = ((t8 >> 9) << 5) + (((t8 >> 6) & 1) << 4) + (t8 & 15);
    const int col = (((t8 >> 7) & 3) << 5) + (((t8 >> 4) & 3) << 3);
    *(short8*)&srec[(size_t)t8 * 8] = *(const short8*)&Ss[row][col];
  }
}

// ---------------------------------------------------------------------------
// A2: in-place exclusive prefix over the 16 ws records of each bh.
__global__ __launch_bounds__(256, 4) void k_prefix(short* __restrict__ ws) {
  const int blk = blockIdx.x;
  const int bh  = blk & 63;              // bh%8 -> XCD, shared with A1/B
  const int p   = blk >> 6;
  const int off = p * 2048 + threadIdx.x * 8;
  short* wb = ws + (size_t)bh * NCHUNK * RECSH;

  float run[8];
#pragma unroll
  for (int s = 0; s < 8; ++s) run[s] = 0.f;
#pragma unroll
  for (int cc = 0; cc < NCHUNK; ++cc) {
    short8* ptr = (short8*)&wb[(size_t)cc * RECSH + off];
    const short8 rv = *ptr;              // read partial S_cc
    short8 ov;
#pragma unroll
    for (int s = 0; s < 8; ++s) ov[s] = f2bf(run[s]);
    *ptr = ov;                           // write exclusive prefix (c=0 -> 0)
#pragma unroll
    for (int s = 0; s < 8; ++s) run[s] += bf2f(rv[s]);
  }
}

// ---------------------------------------------------------------------------
// B: one block per (bh, chunk).  Staging: 12 VGPR-free gload16 (K-blob,
// V-blob, Sb) + 8 Q register loads.  KVS: [0,16K) K-frag blob (later P
// scratch, swz layout), [16K,32K) V-frag blob, [32K,48K) Sb frag blob.
__global__ __launch_bounds__(512, 2) void k_out(
    const float* __restrict__ qin, const short* __restrict__ ws,
    float* out) {
  const int blk = blockIdx.x;
  const int bh  = blk & 63;              // bh%8 -> XCD, shared with A1/A2
  const int c   = blk >> 6;
  const size_t base = (size_t)bh * SEQ * DIM + (size_t)c * CHUNK * DIM;
  const float* qc = qin + base;
  float* oc = out + base;
  const short* rec = (const short*)out + (size_t)(bh * NCHUNK + c) * KVSH;

  __shared__ __align__(16) short KVS[49152];

  const int tid  = threadIdx.x;
  const int wave = tid >> 6;
  const int lane = tid & 63;
  const int q4   = lane >> 4;
  const int l16  = lane & 15;

  // ---- issue ALL async staging first (VGPR-free, deep queue) ----
#pragma unroll
  for (int i = 0; i < 8; ++i) {          // K-blob + V-blob
    const int g = i * 512 + tid;
    gload16(&rec[(size_t)g * 8], &KVS[(size_t)g * 8]);
  }
  const short* sp = ws + (size_t)(bh * NCHUNK + c) * RECSH;
#pragma unroll
  for (int i = 0; i < 4; ++i) {          // S_pre frag blob
    const int g = i * 512 + tid;
    gload16(&sp[(size_t)g * 8], &KVS[32768 + (size_t)g * 8]);
  }

  // ---- Q fragments through registers ----
  const float* qrow = qc + (size_t)(wave * 16 + l16) * DIM + q4 * 8;
  short8 aq[4];
#pragma unroll
  for (int ks = 0; ks < 4; ++ks)
    aq[ks] = pack8(*(const float4*)(qrow + ks * 32),
                   *(const float4*)(qrow + ks * 32 + 4));
  __syncthreads();   // drains vmcnt: KVS fully landed

  floatx4 oacc[8];
#pragma unroll
  for (int tn = 0; tn < 8; ++tn)
#pragma unroll
    for (int r = 0; r < 4; ++r) oacc[tn][r] = 0.f;

  // ---- inter-chunk part: O += Q @ S_pre (B-frags from Sb region) ----
#pragma unroll
  for (int ks = 0; ks < 4; ++ks)
#pragma unroll
    for (int tn = 0; tn < 8; ++tn) {
      const short8 bs = *(const short8*)
          &KVS[32768 + (tn >> 1) * 4096 + ks * 1024 + (tn & 1) * 512 + lane * 8];
      oacc[tn] = MFMA(aq[ks], bs, oacc[tn]);
    }

  // ---- intra-chunk causal scores: B-frags LINEAR from K-blob ----
  floatx4 sacc[8];
#pragma unroll
  for (int tj = 0; tj < 8; ++tj) {
    if (tj > wave) continue;             // wave-uniform, tj static
#pragma unroll
    for (int r = 0; r < 4; ++r) sacc[tj][r] = 0.f;
#pragma unroll
    for (int ks = 0; ks < 4; ++ks) {
      const short8 bk = *(const short8*)&KVS[(tj * 4 + ks) * 512 + lane * 8];
      sacc[tj] = MFMA(aq[ks], bk, sacc[tj]);
    }
  }
  __syncthreads();   // all K-blob reads done; region 0 becomes P scratch

  // ---- masked P into region 0 (swz layout; own 16 rows only) ----
#pragma unroll
  for (int tj = 0; tj < 8; ++tj) {
    if (tj > wave) continue;
#pragma unroll
    for (int r = 0; r < 4; ++r) {
      float val = sacc[tj][r];
      if (tj == wave && l16 > q4 * 4 + r) val = 0.f;   // strict-upper mask
      KVS[swz(wave * 16 + q4 * 4 + r, tj * 16 + l16)] = f2bf(val);
    }
  }
  if ((wave & 1) == 0) {   // even wave: zero tile wave+1 (PV k-step pad)
#pragma unroll
    for (int r = 0; r < 4; ++r)
      KVS[swz(wave * 16 + q4 * 4 + r, (wave + 1) * 16 + l16)] = 0;
  }

  // ---- PV: P rows (same-wave, swz) x V-blob B-frags (linear) ----
  const int kst = (wave + 2) >> 1;
  for (int t = 0; t < kst; ++t) {
    const short8 ap =
        *(const short8*)&KVS[swz(wave * 16 + l16, t * 32 + q4 * 8)];
#pragma unroll
    for (int tn = 0; tn < 8; ++tn) {
      const short8 bv =
          *(const short8*)&KVS[16384 + (t * 8 + tn) * 512 + lane * 8];
      oacc[tn] = MFMA(ap, bv, oacc[tn]);
    }
  }

  // ---- write out tile (fp32), overwriting this block's own record ----
#pragma unroll
  for (int tn = 0; tn < 8; ++tn)
#pragma unroll
    for (int r = 0; r < 4; ++r)
      oc[(size_t)(wave * 16 + q4 * 4 + r) * DIM + tn * 16 + l16] = oacc[tn][r];
}

// ---------------------------------------------------------------------------
extern "C" void kernel_launch(void* const* d_in, const int* in_sizes, int n_in,
                              void* d_out, int out_size, void* d_ws, size_t ws_size,
                              hipStream_t stream) {
  const float* q = (const float*)d_in[0];
  const float* k = (const float*)d_in[1];
  const float* v = (const float*)d_in[2];
  float* out = (float*)d_out;
  (void)in_sizes; (void)n_in; (void)out_size; (void)ws_size;
  // requires ws_size >= 64*16*16384*2 = 32 MiB
  short* ws = (short*)d_ws;

  hipLaunchKernelGGL(k_cstate, dim3(NBH * NCHUNK), dim3(512), 0, stream,
                     k, v, ws, (short*)d_out);
  hipLaunchKernelGGL(k_prefix, dim3(NBH * 8), dim3(256), 0, stream, ws);
  hipLaunchKernelGGL(k_out, dim3(NBH * NCHUNK), dim3(512), 0, stream,
                     q, ws, out);
}